// Round 1
// baseline (776.039 us; speedup 1.0000x reference)
//
#include <hip/hip_runtime.h>

// Problem: B=32, H=W=112 (HW=12544), C=256, K_TOP=128.
// out[b,h,w,c] = x[b,h,w,c] * mask[b,c], mask = top-128 channels of
// (mean_hw(x) @ W + bias)  (sigmoid is monotone -> rank pre-activation).

#define BB 32
#define CC 256
#define HW 12544
#define C4 64                 // float4 per channel row
#define CHUNKS_PER_B 196      // (HW*C4) / 4096 = 802816/4096
#define F4_PER_CHUNK 4096     // 256 threads * 16 float4
#define NBLOCKS (BB * CHUNKS_PER_B)   // 6272

// ---------------- Kernel 1: pooled channel sums (atomic partial) ----------
__global__ __launch_bounds__(256) void pool_partial(const float4* __restrict__ x4,
                                                    float* __restrict__ pooled_sum) {
    const int chunk = blockIdx.x;
    const int b = chunk / CHUNKS_PER_B;
    const long base = (long)chunk * F4_PER_CHUNK;
    const int t = threadIdx.x;

    float4 acc = make_float4(0.f, 0.f, 0.f, 0.f);
#pragma unroll
    for (int k = 0; k < 16; ++k) {
        float4 v = x4[base + t + k * 256];
        acc.x += v.x; acc.y += v.y; acc.z += v.z; acc.w += v.w;
    }

    __shared__ float4 lds[256];
    lds[t] = acc;
    __syncthreads();

    if (t < 64) {
        float4 a = lds[t], b4 = lds[t + 64], c4 = lds[t + 128], d4 = lds[t + 192];
        float sx = a.x + b4.x + c4.x + d4.x;
        float sy = a.y + b4.y + c4.y + d4.y;
        float sz = a.z + b4.z + c4.z + d4.z;
        float sw = a.w + b4.w + c4.w + d4.w;
        float* dst = pooled_sum + b * CC + t * 4;
        atomicAdd(dst + 0, sx);
        atomicAdd(dst + 1, sy);
        atomicAdd(dst + 2, sz);
        atomicAdd(dst + 3, sw);
    }
}

// ---------------- Kernel 2: scores + rank-based top-k mask ----------------
__global__ __launch_bounds__(256) void score_topk(const float* __restrict__ pooled_sum,
                                                  const float* __restrict__ Wm,
                                                  const float* __restrict__ bias,
                                                  float* __restrict__ maskf) {
    const int b = blockIdx.x;
    const int c = threadIdx.x;
    __shared__ float p[CC];
    __shared__ float s[CC];

    p[c] = pooled_sum[b * CC + c] * (1.0f / (float)HW);
    __syncthreads();

    float acc = bias[c];
#pragma unroll 8
    for (int k = 0; k < CC; ++k) {
        acc += p[k] * Wm[k * CC + c];   // coalesced across threads
    }
    // sigmoid is strictly increasing: rank acc directly.
    s[c] = acc;
    __syncthreads();

    int cnt = 0;
    const float sc = acc;
#pragma unroll 8
    for (int j = 0; j < CC; ++j) {
        float sj = s[j];                // broadcast read, conflict-free
        cnt += (sj > sc) || (sj == sc && j < c);
    }
    maskf[b * CC + c] = (cnt < (CC / 2)) ? 1.0f : 0.0f;
}

// ---------------- Kernel 3: broadcast mask multiply -----------------------
__global__ __launch_bounds__(256) void apply_mask(const float4* __restrict__ x4,
                                                  const float* __restrict__ maskf,
                                                  float4* __restrict__ out4) {
    const int chunk = blockIdx.x;
    const int b = chunk / CHUNKS_PER_B;
    const long base = (long)chunk * F4_PER_CHUNK;
    const int t = threadIdx.x;

    // Thread's channel quad is fixed: c4 = t & 63. Mask row is L2/L3 hot.
    const float4 m = *(const float4*)(maskf + b * CC + (t & 63) * 4);

#pragma unroll
    for (int k = 0; k < 16; ++k) {
        long i = base + t + k * 256;
        float4 v = x4[i];
        v.x *= m.x; v.y *= m.y; v.z *= m.z; v.w *= m.w;
        out4[i] = v;
    }
}

extern "C" void kernel_launch(void* const* d_in, const int* in_sizes, int n_in,
                              void* d_out, int out_size, void* d_ws, size_t ws_size,
                              hipStream_t stream) {
    const float* x  = (const float*)d_in[0];
    const float* Wm = (const float*)d_in[1];
    const float* bs = (const float*)d_in[2];
    float* out = (float*)d_out;

    float* pooled_sum = (float*)d_ws;                 // [32*256] f32
    float* maskf      = (float*)d_ws + BB * CC;       // [32*256] f32

    // ws is poisoned 0xAA each call -> zero the accumulator region.
    hipMemsetAsync(pooled_sum, 0, BB * CC * sizeof(float), stream);

    pool_partial<<<NBLOCKS, 256, 0, stream>>>((const float4*)x, pooled_sum);
    score_topk<<<BB, 256, 0, stream>>>(pooled_sum, Wm, bs, maskf);
    apply_mask<<<NBLOCKS, 256, 0, stream>>>((const float4*)x, maskf, (float4*)out);
}

// Round 3
// 755.757 us; speedup vs baseline: 1.0268x; 1.0268x over previous
//
#include <hip/hip_runtime.h>

// B=32, H=W=112 (HW=12544), C=256, K_TOP=128.
// out[b,h,w,c] = x[b,h,w,c] * mask[b,c], mask = top-128 channels of
// (mean_hw(x) @ W + b); sigmoid monotone -> rank pre-activation.
//
// Traffic plan: pool reads x (411 MB, streams through L3); apply reads x in
// REVERSE chunk order (tail of x is L3-hot) with non-temporal output stores
// so out-writes don't evict x from L3.

#define BB 32
#define CC 256
#define HW 12544
#define RPB 196               // chunks per batch sample
#define F4_PER_CHUNK 4096     // 256 threads * 16 float4 = 64 KB
#define NBLOCKS (BB * RPB)    // 6272

typedef float nfloat4 __attribute__((ext_vector_type(4)));  // native vec for NT store

// ---------------- Kernel 1: per-chunk channel partial sums ----------------
// partial[chunk][c] for chunk = b*RPB + r  (no atomics, no init needed)
__global__ __launch_bounds__(256) void pool_partial(const float4* __restrict__ x4,
                                                    float4* __restrict__ partial4) {
    const int chunk = blockIdx.x;
    const long base = (long)chunk * F4_PER_CHUNK;
    const int t = threadIdx.x;

    float4 acc = make_float4(0.f, 0.f, 0.f, 0.f);
#pragma unroll
    for (int k = 0; k < 16; ++k) {
        float4 v = x4[base + t + k * 256];
        acc.x += v.x; acc.y += v.y; acc.z += v.z; acc.w += v.w;
    }

    __shared__ float4 lds[256];
    lds[t] = acc;
    __syncthreads();

    if (t < 64) {
        float4 a = lds[t], b4 = lds[t + 64], c4 = lds[t + 128], d4 = lds[t + 192];
        float4 s;
        s.x = a.x + b4.x + c4.x + d4.x;
        s.y = a.y + b4.y + c4.y + d4.y;
        s.z = a.z + b4.z + c4.z + d4.z;
        s.w = a.w + b4.w + c4.w + d4.w;
        partial4[(long)chunk * (CC / 4) + t] = s;   // channels 4t..4t+3
    }
}

// ---------------- Kernel 2: reduce partials, matmul, rank-top-k mask ------
__global__ __launch_bounds__(256) void score_topk(const float* __restrict__ partial,
                                                  const float* __restrict__ Wm,
                                                  const float* __restrict__ bias,
                                                  float* __restrict__ maskf) {
    const int b = blockIdx.x;
    const int c = threadIdx.x;
    __shared__ float p[CC];
    __shared__ float s[CC];

    // reduce 196 partials for (b, c) — coalesced across c
    float sum = 0.f;
    const float* pb = partial + (long)b * RPB * CC + c;
#pragma unroll 4
    for (int r = 0; r < RPB; ++r) sum += pb[r * CC];
    p[c] = sum * (1.0f / (float)HW);
    __syncthreads();

    float acc = bias[c];
#pragma unroll 8
    for (int k = 0; k < CC; ++k) {
        acc += p[k] * Wm[k * CC + c];   // coalesced across threads
    }
    s[c] = acc;                          // sigmoid monotone: rank acc
    __syncthreads();

    int cnt = 0;
    const float sc = acc;
#pragma unroll 8
    for (int j = 0; j < CC; ++j) {
        float sj = s[j];                 // LDS broadcast
        cnt += (sj > sc) || (sj == sc && j < c);
    }
    maskf[b * CC + c] = (cnt < (CC / 2)) ? 1.0f : 0.0f;
}

// ---------------- Kernel 3: reversed-order mask multiply ------------------
__global__ __launch_bounds__(256) void apply_mask(const float4* __restrict__ x4,
                                                  const float* __restrict__ maskf,
                                                  nfloat4* __restrict__ out4) {
    // Reverse chunk order: the tail of x (read last by pool) is L3-resident.
    const int chunk = (NBLOCKS - 1) - blockIdx.x;
    const int b = chunk / RPB;
    const long base = (long)chunk * F4_PER_CHUNK;
    const int t = threadIdx.x;

    const float4 m = *(const float4*)(maskf + b * CC + (t & 63) * 4);

#pragma unroll
    for (int k = 0; k < 16; ++k) {
        long i = base + t + k * 256;
        float4 v = x4[i];
        nfloat4 r;
        r.x = v.x * m.x; r.y = v.y * m.y; r.z = v.z * m.z; r.w = v.w * m.w;
        __builtin_nontemporal_store(r, &out4[i]);  // don't evict x from L3
    }
}

extern "C" void kernel_launch(void* const* d_in, const int* in_sizes, int n_in,
                              void* d_out, int out_size, void* d_ws, size_t ws_size,
                              hipStream_t stream) {
    const float* x  = (const float*)d_in[0];
    const float* Wm = (const float*)d_in[1];
    const float* bs = (const float*)d_in[2];
    float* out = (float*)d_out;

    float* partial = (float*)d_ws;                        // [6272][256] f32 = 6.4 MB
    float* maskf   = (float*)d_ws + (long)NBLOCKS * CC;   // [32][256] f32

    pool_partial<<<NBLOCKS, 256, 0, stream>>>((const float4*)x, (float4*)partial);
    score_topk<<<BB, 256, 0, stream>>>(partial, Wm, bs, maskf);
    apply_mask<<<NBLOCKS, 256, 0, stream>>>((const float4*)x, maskf, (nfloat4*)out);
}

// Round 4
// 746.912 us; speedup vs baseline: 1.0390x; 1.0118x over previous
//
#include <hip/hip_runtime.h>

// B=32, H=W=112 (HW=12544), C=256, K_TOP=128.
// out[b,h,w,c] = x[b,h,w,c] * mask[b,c], mask = top-128 channels of
// (mean_hw(x) @ W + b); sigmoid monotone -> rank pre-activation.
//
// Structure: pool (atomic channel sums, x streams through L3) -> score
// (tiny matmul + rank) -> apply (REVERSE chunk order so the x tail pool
// left in L3 is re-hit; NT loads since x is never re-read; NT stores so
// out doesn't evict x from L3).

#define BB 32
#define CC 256
#define HW 12544
#define RPB 196               // chunks per batch sample
#define F4_PER_CHUNK 4096     // 256 threads * 16 float4 = 64 KB
#define NBLOCKS (BB * RPB)    // 6272

typedef float nfloat4 __attribute__((ext_vector_type(4)));  // native vec for NT ld/st

// ---------------- Kernel 1: pooled channel sums (atomic) ------------------
__global__ __launch_bounds__(256) void pool_atomic(const float4* __restrict__ x4,
                                                   float* __restrict__ pooled_sum) {
    const int chunk = blockIdx.x;
    const int b = chunk / RPB;
    const long base = (long)chunk * F4_PER_CHUNK;
    const int t = threadIdx.x;

    float4 acc = make_float4(0.f, 0.f, 0.f, 0.f);
#pragma unroll
    for (int k = 0; k < 16; ++k) {
        float4 v = x4[base + t + k * 256];
        acc.x += v.x; acc.y += v.y; acc.z += v.z; acc.w += v.w;
    }

    __shared__ float4 lds[256];
    lds[t] = acc;
    __syncthreads();

    if (t < 64) {
        float4 a = lds[t], b4 = lds[t + 64], c4 = lds[t + 128], d4 = lds[t + 192];
        float* dst = pooled_sum + b * CC + t * 4;   // 8192 addresses, ~196 adds each
        atomicAdd(dst + 0, a.x + b4.x + c4.x + d4.x);
        atomicAdd(dst + 1, a.y + b4.y + c4.y + d4.y);
        atomicAdd(dst + 2, a.z + b4.z + c4.z + d4.z);
        atomicAdd(dst + 3, a.w + b4.w + c4.w + d4.w);
    }
}

// ---------------- Kernel 2: scores + rank-based top-k mask ----------------
__global__ __launch_bounds__(256) void score_topk(const float* __restrict__ pooled_sum,
                                                  const float* __restrict__ Wm,
                                                  const float* __restrict__ bias,
                                                  float* __restrict__ maskf) {
    const int b = blockIdx.x;
    const int c = threadIdx.x;
    __shared__ float p[CC];
    __shared__ float s[CC];

    p[c] = pooled_sum[b * CC + c] * (1.0f / (float)HW);
    __syncthreads();

    float acc = bias[c];
#pragma unroll 16
    for (int k = 0; k < CC; ++k) {
        acc += p[k] * Wm[k * CC + c];   // coalesced across threads; W L2-hot
    }
    s[c] = acc;                          // sigmoid monotone: rank acc
    __syncthreads();

    int cnt = 0;
    const float sc = acc;
#pragma unroll 16
    for (int j = 0; j < CC; ++j) {
        float sj = s[j];                 // LDS broadcast
        cnt += (sj > sc) || (sj == sc && j < c);
    }
    maskf[b * CC + c] = (cnt < (CC / 2)) ? 1.0f : 0.0f;
}

// ---------------- Kernel 3: reversed-order mask multiply ------------------
__global__ __launch_bounds__(256) void apply_mask(const nfloat4* __restrict__ x4,
                                                  const float* __restrict__ maskf,
                                                  nfloat4* __restrict__ out4) {
    // Reverse chunk order: the tail of x (read last by pool) is L3-resident.
    const int chunk = (NBLOCKS - 1) - blockIdx.x;
    const int b = chunk / RPB;
    const long base = (long)chunk * F4_PER_CHUNK;
    const int t = threadIdx.x;

    const float4 m = *(const float4*)(maskf + b * CC + (t & 63) * 4);

#pragma unroll
    for (int k = 0; k < 16; ++k) {
        long i = base + t + k * 256;
        nfloat4 v = __builtin_nontemporal_load(&x4[i]);   // x never re-read
        nfloat4 r;
        r.x = v.x * m.x; r.y = v.y * m.y; r.z = v.z * m.z; r.w = v.w * m.w;
        __builtin_nontemporal_store(r, &out4[i]);         // don't evict x from L3
    }
}

extern "C" void kernel_launch(void* const* d_in, const int* in_sizes, int n_in,
                              void* d_out, int out_size, void* d_ws, size_t ws_size,
                              hipStream_t stream) {
    const float* x  = (const float*)d_in[0];
    const float* Wm = (const float*)d_in[1];
    const float* bs = (const float*)d_in[2];
    float* out = (float*)d_out;

    float* pooled_sum = (float*)d_ws;                 // [32*256] f32 = 32 KB
    float* maskf      = (float*)d_ws + BB * CC;       // [32*256] f32

    // ws is poisoned 0xAA each call -> zero the atomic accumulator (32 KB, ~µs).
    hipMemsetAsync(pooled_sum, 0, BB * CC * sizeof(float), stream);

    pool_atomic<<<NBLOCKS, 256, 0, stream>>>((const float4*)x, pooled_sum);
    score_topk<<<BB, 256, 0, stream>>>(pooled_sum, Wm, bs, maskf);
    apply_mask<<<NBLOCKS, 256, 0, stream>>>((const nfloat4*)x, maskf, (nfloat4*)out);
}